// Round 13
// baseline (10987.560 us; speedup 1.0000x reference)
//
#include <hip/hip_runtime.h>
#include <hip/hip_fp16.h>

#define TT 2048
typedef unsigned int uint32;
typedef unsigned long long uint64;
typedef unsigned short ushort;

typedef _Float16 half2v __attribute__((ext_vector_type(2)));

#if defined(__has_builtin)
#  if __has_builtin(__builtin_amdgcn_fdot2)
#    define HAVE_DOT2 1
#  endif
#endif
#ifndef HAVE_DOT2
#  define HAVE_DOT2 0
#endif

// ---- d_ws layout ----
// WREGH: uint32[2][176][512]   packed fp16 weight pairs      (720896 B)
// exS  : uint64[2][64][2][64]  {tag,2xfp16} s-half channel   (131072 B)
// exX  : uint64[2][64][2][128] {tag,2xfp16} x-half channel   (262144 B)
#define WREG_N (2 * 176 * 512)
#define EXS_N  (2 * 64 * 2 * 64)
#define EXX_N  (2 * 64 * 2 * 128)
#define ZQ_N   (EXS_N + EXX_N)

__device__ __forceinline__ float dot2(uint32 a, uint32 w, float c)
{
#if HAVE_DOT2
    return __builtin_amdgcn_fdot2(__builtin_bit_cast(half2v, a),
                                  __builtin_bit_cast(half2v, w), c, false);
#else
    half2v av = __builtin_bit_cast(half2v, a);
    half2v wv = __builtin_bit_cast(half2v, w);
    c = fmaf((float)av.x, (float)wv.x, c);
    return fmaf((float)av.y, (float)wv.y, c);
#endif
}

__device__ __forceinline__ uint32 pkh(float a, float b)
{
    __half ha = __float2half(a), hb = __float2half(b);
    ushort ua = *reinterpret_cast<ushort*>(&ha);
    ushort ub = *reinterpret_cast<ushort*>(&hb);
    return (uint32)ua | ((uint32)ub << 16);
}

// full cat col: [x 0:512 | s 512:768 | I 768:896]
__device__ __forceinline__ float getFull(const float* __restrict__ W_ih,
                                         const float* __restrict__ W_hh,
                                         int j, int k)
{
    if (k < 512) return W_ih[j * 640 + k];
    if (k < 768) return W_hh[j * 256 + (k - 512)];
    return W_ih[j * 640 + 512 + (k - 768)];
}

// act pair index P for A-slot i of thread (q = tid&3), member g.
// act pair layout: [x 0:256 | s 256:384 | I 384:448]; pair P <-> cat k = 2P.
// q-interleaved at uint4 granularity so per-wave reads hit 4 distinct banks.
__device__ __forceinline__ int aslotP(int g, int q, int i)
{
    if (i < 32)  return 256 + 16 * (i >> 2) + 4 * q + (i & 3);              // s
    if (i < 48)  { int i2 = i - 32; return 384 + 16 * (i2 >> 2) + 4 * q + (i2 & 3); } // I
    if (i < 80)  { int i2 = i - 48; return 128 * g + 16 * (i2 >> 2) + 4 * q + (i2 & 3); } // x-own
    { int i2 = i - 80; return 128 * (1 - g) + 16 * (i2 >> 2) + 4 * q + (i2 & 3); }        // x-peer
}

__global__ void prep_kernel(const float* __restrict__ W_ih,
                            const float* __restrict__ W_hh,
                            const float* __restrict__ W_out,
                            uint32* __restrict__ WREGH,
                            uint64* __restrict__ zbase)
{
    int idx = blockIdx.x * blockDim.x + threadIdx.x;
    if (idx < WREG_N) {
        int tid = idx & 511;
        int r   = idx >> 9;       // g*176 + slot
        int g   = r / 176;
        int i   = r % 176;
        float lo, hi;
        if (i < 112) {            // A: thread (jloc = tid>>2, q = tid&3)
            int q = tid & 3, jloc = tid >> 2;
            int j = 128 * g + jloc;
            int k = 2 * aslotP(g, q, i);
            lo = getFull(W_ih, W_hh, j, k);
            hi = getFull(W_ih, W_hh, j, k + 1);
        } else {                  // B: thread (nloc = tid>>1, hh = tid&1)
            int ib = i - 112;     // [0,64)
            int hh = tid & 1, nloc = tid >> 1;
            int n  = 256 * g + nloc;
            int sp = (ib < 32) ? (64 * g + 32 * hh + ib)
                               : (64 * (1 - g) + 32 * hh + (ib - 32));
            lo = W_out[n * 256 + 2 * sp];
            hi = W_out[n * 256 + 2 * sp + 1];
        }
        WREGH[idx] = pkh(lo, hi);
    } else if (idx < WREG_N + ZQ_N) {
        zbase[idx - WREG_N] = 0ULL;   // channel tags start 0 (ws is 0xAA-poisoned)
    }
}

// LDS-only barrier: does NOT drain vmcnt (global loads/stores stay in flight).
__device__ __forceinline__ void bar_lds()
{
    asm volatile("s_waitcnt lgkmcnt(0)" ::: "memory");
    __builtin_amdgcn_s_barrier();
    asm volatile("" ::: "memory");
}

__device__ __forceinline__ uint64 ldA(const uint64* p)
{
    return __hip_atomic_load(p, __ATOMIC_RELAXED, __HIP_MEMORY_SCOPE_AGENT);
}
__device__ __forceinline__ void stA(uint64* p, uint64 v)
{
    __hip_atomic_store(p, v, __ATOMIC_RELAXED, __HIP_MEMORY_SCOPE_AGENT);
}

__global__ __launch_bounds__(512, 1)
void scan_kernel(const float* __restrict__ I,
                 const float* __restrict__ b_ih, const float* __restrict__ b_hh,
                 const float* __restrict__ b_out, const float* __restrict__ A,
                 const uint32* __restrict__ WREGH,
                 uint64* exS, uint64* exX,
                 float* __restrict__ out)
{
    // act pairs (fp16x2): [x 0:256 | s 256:384 | I 384:448], parity dbuf
    __shared__ uint4 apk4[2][112];
    __shared__ uint4 s4u[36];         // s pairs in 4 runs of 8 uint4, stride 9 (pad)
    __shared__ float xf32[256];       // exact f32 x state, own n-half

    const int tid = threadIdx.x;
    const int bid = blockIdx.x;
    const int e   = bid & 63;     // batch element
    const int g   = bid >> 6;     // gang member (0/1)
    const int gp  = 1 - g;

    // ---- weights -> VGPR (static-indexed, fully unrolled, pinned) ----
    uint32 wA[112], wB[64];
    const uint32* wsrc = WREGH + (size_t)g * (176 * 512) + tid;
    #pragma unroll
    for (int i = 0; i < 112; ++i) { wA[i] = wsrc[(size_t)i * 512]; asm("" : "+v"(wA[i])); }
    #pragma unroll
    for (int i = 0; i < 64;  ++i) { wB[i] = wsrc[(size_t)(112 + i) * 512]; asm("" : "+v"(wB[i])); }

    const int q    = tid & 3;     // A k-quarter
    const int jloc = tid >> 2;    // A local output row [0,128)
    const int hh   = tid & 1;     // B k-half
    const int nloc = tid >> 1;    // B local output row [0,256)

    const float bs   = ((tid & 3) == 0) ? (b_ih[128 * g + jloc] + b_hh[128 * g + jloc]) : 0.f;
    const float bo_r = ((tid & 1) == 0) ? b_out[256 * g + nloc] : 0.f;
    const float Av_r = ((tid & 1) == 0) ? A[256 * g + nloc] : 0.f;

    const size_t iBase   = (size_t)e * TT * 128;
    const size_t outBase = (size_t)e * TT * 512 + 256 * g;

    {   // init buffer 0: x=0 (dwords 0..255), s=0 (256..383), I(0) (384..447)
        uint32* a0p = (uint32*)&apk4[0][0];
        if (tid < 384) a0p[tid] = 0u;
        else if (tid < 448) {
            int m = tid - 384;
            a0p[tid] = pkh(I[iBase + 2 * m], I[iBase + 2 * m + 1]);
        }
        if (tid < 256) xf32[tid] = 0.f;
    }
    __syncthreads();

    for (int t = 0; t < TT; ++t) {
        const int par = t & 1;
        const uint4* rdp   = apk4[par];
        uint32*      rdp_d = (uint32*)apk4[par];
        uint32*      wrp   = (uint32*)apk4[par ^ 1];

        // I(t+1): issue loads at step top (hides HBM under whole step)
        float2 iv2 = make_float2(0.f, 0.f);
        if (tid < 64) {
            int tl = (t + 1 < TT) ? (t + 1) : t;
            iv2 = *(const float2*)(I + iBase + (size_t)tl * 128 + 2 * tid);
        }

        // channel pointers for this step
        const uint32 tgx = (uint32)t;        // x produced at t-1 carries tag t
        const uint32 tgs = (uint32)(t + 1);  // s produced this step
        uint64* exXc = exX + ((size_t)((t & 1) * 64 + e) * 2) * 128;        // consume par = t&1
        uint64* exXp = exX + ((size_t)(((t + 1) & 1) * 64 + e) * 2) * 128;  // produce par = (t+1)&1
        uint64* exSc = exS + ((size_t)((t & 1) * 64 + e) * 2) * 64;

        uint64* pxc = exXc + gp * 128 + (tid >> 2);   // peer x word (pollers tid&3==0)
        uint64* psc = exSc + gp * 64 + (tid >> 3);    // peer s word (pollers tid&7==0)

        // ---- phase A-own: s, I, x-own slots (20 uint4 groups, 80 dot2) ----
        float a0 = 0.f, a1 = 0.f;
        uint64 sx0 = 0, sx1 = 0;
        #pragma unroll
        for (int gi = 0; gi < 10; ++gi) {
            int u4 = (gi < 8) ? (64 + q + 4 * gi) : (96 + q + 4 * (gi - 8));
            uint4 av = rdp[u4];
            a0 = dot2(av.x, wA[4 * gi + 0], a0);
            a1 = dot2(av.y, wA[4 * gi + 1], a1);
            a0 = dot2(av.z, wA[4 * gi + 2], a0);
            a1 = dot2(av.w, wA[4 * gi + 3], a1);
        }
        if ((tid & 3) == 0 && t > 0) sx0 = ldA(pxc);   // snapshot #1 (in flight)
        #pragma unroll
        for (int gi = 10; gi < 20; ++gi) {
            int u4 = (gi < 12) ? (96 + q + 4 * (gi - 8)) : (32 * g + q + 4 * (gi - 12));
            uint4 av = rdp[u4];
            a0 = dot2(av.x, wA[4 * gi + 0], a0);
            a1 = dot2(av.y, wA[4 * gi + 1], a1);
            a0 = dot2(av.z, wA[4 * gi + 2], a0);
            a1 = dot2(av.w, wA[4 * gi + 3], a1);
        }
        if ((tid & 3) == 0 && t > 0) sx1 = ldA(pxc);   // snapshot #2

        // resolve peer-x (newest first, slowpoll fallback), write into rdp
        if ((tid & 3) == 0 && t > 0) {
            uint64 v;
            if      ((uint32)(sx1 >> 32) == tgx) v = sx1;
            else if ((uint32)(sx0 >> 32) == tgx) v = sx0;
            else do { v = ldA(pxc); } while ((uint32)(v >> 32) != tgx);
            rdp_d[128 * gp + (tid >> 2)] = (uint32)v;
        }
        bar_lds();                                   // (1) peer-x visible

        // ---- phase A-peer: x-peer slots (8 uint4 groups, 32 dot2) ----
        #pragma unroll
        for (int gi = 20; gi < 28; ++gi) {
            int u4 = 32 * gp + q + 4 * (gi - 20);
            uint4 av = rdp[u4];
            a0 = dot2(av.x, wA[4 * gi + 0], a0);
            a1 = dot2(av.y, wA[4 * gi + 1], a1);
            a0 = dot2(av.z, wA[4 * gi + 2], a0);
            a1 = dot2(av.w, wA[4 * gi + 3], a1);
        }
        float acc = a0 + a1;
        acc += __shfl_xor(acc, 1);
        acc += __shfl_xor(acc, 2);                   // full pre at all 4 q-lanes

        float sn = 0.f;
        if ((tid & 3) == 0) {
            float pre = acc + bs;
            // tanh(x) = 1 - 2/(exp(2x)+1): exact identity, branch-free
            float ex2 = __expf(2.f * pre);
            sn = 1.f - 2.f / (ex2 + 1.f);
        }
        {   // pack s pairs {s[2m], s[2m+1]}: lanes 8m (jloc=2m) & 8m+4 (jloc=2m+1)
            float sno = __shfl_xor(sn, 4);
            if ((tid & 7) == 0) {
                int m = tid >> 3;                    // [0,64)
                uint32 sp2 = pkh(sn, sno);
                // STORE to peer first (starts the flight ASAP)
                stA(exSc + g * 64 + m, ((uint64)tgs << 32) | (uint64)sp2);
                // own-s into s4u run + next-step act s-slots
                ((uint32*)s4u)[(2 * g + (m >> 5)) * 36 + (m & 31)] = sp2;
                wrp[256 + 64 * g + m] = sp2;
            }
        }
        bar_lds();                                   // (2) own-s visible for B-own

        // ---- phase B-own: own-s columns (8 uint4 groups, 32 dot2) ----
        float c0 = 0.f, c1 = 0.f;
        uint64 ss0 = 0, ss1 = 0;
        if ((tid & 7) == 0) ss0 = ldA(psc);          // s snapshot #1
        #pragma unroll
        for (int ii = 0; ii < 8; ++ii) {
            uint4 sv = s4u[(2 * g + hh) * 9 + ii];
            c0 = dot2(sv.x, wB[4 * ii + 0], c0);
            c1 = dot2(sv.y, wB[4 * ii + 1], c1);
            c0 = dot2(sv.z, wB[4 * ii + 2], c0);
            c1 = dot2(sv.w, wB[4 * ii + 3], c1);
        }
        if ((tid & 7) == 0) ss1 = ldA(psc);          // s snapshot #2

        // resolve peer-s, write s4u peer runs + next-step act s-slots
        if ((tid & 7) == 0) {
            uint64 v;
            if      ((uint32)(ss1 >> 32) == tgs) v = ss1;
            else if ((uint32)(ss0 >> 32) == tgs) v = ss0;
            else do { v = ldA(psc); } while ((uint32)(v >> 32) != tgs);
            int m = tid >> 3;
            ((uint32*)s4u)[(2 * gp + (m >> 5)) * 36 + (m & 31)] = (uint32)v;
            wrp[256 + 64 * gp + m] = (uint32)v;
        }
        bar_lds();                                   // (3) peer-s visible

        // ---- phase B-peer: peer-s columns (8 uint4 groups, 32 dot2) ----
        #pragma unroll
        for (int ii = 0; ii < 8; ++ii) {
            uint4 sv = s4u[(2 * gp + hh) * 9 + ii];
            c0 = dot2(sv.x, wB[32 + 4 * ii + 0], c0);
            c1 = dot2(sv.y, wB[32 + 4 * ii + 1], c1);
            c0 = dot2(sv.z, wB[32 + 4 * ii + 2], c0);
            c1 = dot2(sv.w, wB[32 + 4 * ii + 3], c1);
        }
        float f = c0 + c1;
        f += __shfl_xor(f, 1);                       // hh pair -> full k-sum

        float xn = 0.f;
        if ((tid & 1) == 0) {
            float ff = fmaxf(f + bo_r, 0.f);
            float xo = xf32[nloc];                   // exact f32 state in/out
            xn = (xo + 0.1f * ff * Av_r) / (1.1f + 0.1f * ff);
            xf32[nloc] = xn;                         // same-thread RMW: no race
            out[outBase + (size_t)t * 512 + nloc] = xn;
        }
        {   // pack x pairs {x[2m], x[2m+1]}: lanes 4m & 4m+2
            float xno = __shfl_xor(xn, 2);
            if ((tid & 3) == 0) {
                int m = tid >> 2;                    // [0,128)
                uint32 xp2 = pkh(xn, xno);
                // STORE to peer first (flight overlaps next A-own)
                stA(exXp + g * 128 + m, ((uint64)(t + 1) << 32) | (uint64)xp2);
                wrp[128 * g + m] = xp2;              // own-x for next A
            }
        }
        if (tid < 64) wrp[384 + tid] = pkh(iv2.x, iv2.y);   // stage I(t+1)
        bar_lds();                                   // (4) state ready for next A
    }
}

extern "C" void kernel_launch(void* const* d_in, const int* in_sizes, int n_in,
                              void* d_out, int out_size, void* d_ws, size_t ws_size,
                              hipStream_t stream)
{
    const float* I     = (const float*)d_in[0];
    const float* W_ih  = (const float*)d_in[1];
    const float* W_hh  = (const float*)d_in[2];
    const float* b_ih  = (const float*)d_in[3];
    const float* b_hh  = (const float*)d_in[4];
    const float* W_out = (const float*)d_in[5];
    const float* b_out = (const float*)d_in[6];
    const float* A     = (const float*)d_in[7];

    uint32* WREGH = (uint32*)d_ws;
    uint64* zbase = (uint64*)((uint32*)d_ws + WREG_N);   // exS | exX
    uint64* exS   = zbase;
    uint64* exX   = zbase + EXS_N;

    const int total = WREG_N + ZQ_N;
    prep_kernel<<<(total + 1023) / 1024, 1024, 0, stream>>>(W_ih, W_hh, W_out,
                                                            WREGH, zbase);
    scan_kernel<<<128, 512, 0, stream>>>(I, b_ih, b_hh, b_out, A,
                                         WREGH, exS, exX, (float*)d_out);
}

// Round 14
// 4302.928 us; speedup vs baseline: 2.5535x; 2.5535x over previous
//
#include <hip/hip_runtime.h>
#include <hip/hip_fp16.h>

#define TT 2048
typedef unsigned int uint32;
typedef unsigned long long uint64;
typedef unsigned short ushort;

typedef _Float16 half2v __attribute__((ext_vector_type(2)));

#if defined(__has_builtin)
#  if __has_builtin(__builtin_amdgcn_fdot2)
#    define HAVE_DOT2 1
#  endif
#endif
#ifndef HAVE_DOT2
#  define HAVE_DOT2 0
#endif

// ---- d_ws layout ----
// WREGH: uint32[2][176][512]   packed fp16 weight pairs   (720896 B)
// exS  : uint64[2][64][2][256] {tag,f32} exchange         (524288 B)
#define WREG_N (2 * 176 * 512)       // 180224 dwords
#define EXA_N  (2 * 64 * 2 * 256)    // 65536 qwords

__device__ __forceinline__ float dot2(uint32 a, uint32 w, float c)
{
#if HAVE_DOT2
    return __builtin_amdgcn_fdot2(__builtin_bit_cast(half2v, a),
                                  __builtin_bit_cast(half2v, w), c, false);
#else
    half2v av = __builtin_bit_cast(half2v, a);
    half2v wv = __builtin_bit_cast(half2v, w);
    c = fmaf((float)av.x, (float)wv.x, c);
    return fmaf((float)av.y, (float)wv.y, c);
#endif
}

__device__ __forceinline__ uint32 pkh(float a, float b)
{
    __half ha = __float2half(a), hb = __float2half(b);
    ushort ua = *reinterpret_cast<ushort*>(&ha);
    ushort ub = *reinterpret_cast<ushort*>(&hb);
    return (uint32)ua | ((uint32)ub << 16);
}

// Member g's cat slice, k_slice in [0,448):
//  [0,256) -> x cols 256g+k ; [256,384) -> s cols 128g+(k-256) ; [384,448) -> I cols 64g+(k-384)
__device__ __forceinline__ float getSlice(const float* __restrict__ W_ih,
                                          const float* __restrict__ W_hh,
                                          int g, int j, int k)
{
    if (k < 256) return W_ih[j * 640 + 256 * g + k];
    if (k < 384) return W_hh[j * 256 + 128 * g + (k - 256)];
    return W_ih[j * 640 + 512 + 64 * g + (k - 384)];
}

// Per-thread weight layout: identical to round 10 (proven absmax 0.0039).
__global__ void prep_kernel(const float* __restrict__ W_ih,
                            const float* __restrict__ W_hh,
                            const float* __restrict__ W_out,
                            uint32* __restrict__ WREGH,
                            uint64* __restrict__ exS)
{
    int idx = blockIdx.x * blockDim.x + threadIdx.x;
    if (idx < WREG_N) {
        int tid  = idx & 511;
        int q    = idx >> 9;       // g*176 + slot
        int g    = q / 176;
        int slot = q % 176;
        float lo, hi;
        if (slot < 112) {
            int j = tid >> 1, h = tid & 1;
            int k0 = 2 * (112 * h + slot);
            lo = getSlice(W_ih, W_hh, g, j, k0);
            hi = getSlice(W_ih, W_hh, g, j, k0 + 1);
        } else {
            int s  = slot - 112;
            int ii = s >> 2, m = s & 3;
            int nloc = tid >> 1, hh = tid & 1;
            int n  = 256 * g + nloc;
            int k0 = 128 * hh + 8 * ii + 2 * m;
            lo = W_out[n * 256 + k0];
            hi = W_out[n * 256 + k0 + 1];
        }
        WREGH[idx] = pkh(lo, hi);
    } else if (idx < WREG_N + EXA_N) {
        exS[idx - WREG_N] = 0ULL;   // tags must start 0 (ws is 0xAA-poisoned)
    }
}

// LDS-only barrier: does NOT drain vmcnt (global ops stay in flight).
__device__ __forceinline__ void bar_lds()
{
    asm volatile("s_waitcnt lgkmcnt(0)" ::: "memory");
    __builtin_amdgcn_s_barrier();
    asm volatile("" ::: "memory");
}

__global__ __launch_bounds__(512, 2)
void scan_kernel(const float* __restrict__ I,
                 const float* __restrict__ b_ih, const float* __restrict__ b_hh,
                 const float* __restrict__ b_out, const float* __restrict__ A,
                 const uint32* __restrict__ WREGH,
                 uint64* exS,
                 float* __restrict__ out)
{
    // member-slice act, packed fp16 pairs, parity double-buffered:
    //   pairs [0,128)=x-half  [128,192)=s-half  [192,224)=I-half
    __shared__ uint4 apk4[2][56];
    __shared__ uint4 s4pk[34];        // FULL s packed pairs, PADDED: run stride
                                      // 17 uint4 kills the 256B same-bank hit
    __shared__ float xf32[256];       // exact f32 x state (own n-half)

    const int tid = threadIdx.x;
    const int bid = blockIdx.x;
    const int b   = bid & 63;     // batch element
    const int g   = bid >> 6;     // gang member (0/1)

    // ---- weights -> VGPR (static-indexed, fully unrolled, pinned) ----
    uint32 wA[112], wB[64];
    const uint32* wsrc = WREGH + (size_t)g * (176 * 512) + tid;
    #pragma unroll
    for (int i = 0; i < 112; ++i) { wA[i] = wsrc[(size_t)i * 512]; asm("" : "+v"(wA[i])); }
    #pragma unroll
    for (int i = 0; i < 64;  ++i) { wB[i] = wsrc[(size_t)(112 + i) * 512]; asm("" : "+v"(wB[i])); }

    const int h    = tid & 1;     // A k-half within lane pair (224 k each)
    const int jA   = tid >> 1;    // A output row [0,256)
    const int hh   = tid & 1;     // B k-half (128 k each)
    const int nloc = tid >> 1;    // B output row within member half

    const float bs   = ((tid & 1) == 0) ? (b_ih[jA] + b_hh[jA]) : 0.f;
    const float bo_r = ((tid & 1) == 0) ? b_out[256 * g + nloc] : 0.f;
    const float Av_r = ((tid & 1) == 0) ? A[256 * g + nloc] : 0.f;

    const size_t iBase   = (size_t)b * TT * 128 + 64 * g;
    const size_t outBase = (size_t)b * TT * 512 + 256 * g;

    {   // init buffer 0: x=0 (pairs 0..127), s=0 (128..191), I(0) (192..223)
        uint32* a0p = (uint32*)&apk4[0][0];
        if (tid < 192) a0p[tid] = 0u;
        else if (tid < 224) {
            int m = tid - 192;
            a0p[tid] = pkh(I[iBase + 2 * m], I[iBase + 2 * m + 1]);
        }
        if (tid < 256) xf32[tid] = 0.f;
    }
    __syncthreads();

    for (int t = 0; t < TT; ++t) {
        const int par = t & 1;
        const uint4* rdp = apk4[par];
        uint32*      wrp = (uint32*)apk4[par ^ 1];

        // I(t+1): issue loads early (hides HBM under compute + sync)
        float2 iv2 = make_float2(0.f, 0.f);
        if (tid < 32) {
            int tl = (t + 1 < TT) ? (t + 1) : t;
            iv2 = *(const float2*)(I + iBase + (size_t)tl * 128 + 2 * tid);
        }

        // ---- phase A: pre[jA] partial over this member's 448-k slice ----
        float a0 = 0.f, a1 = 0.f, a2 = 0.f, a3 = 0.f;   // 4 accs: break dep chain
        #pragma unroll
        for (int i = 0; i < 28; ++i) {
            uint4 av = rdp[28 * h + i];      // 2 addrs/wave -> LDS broadcast
            a0 = dot2(av.x, wA[4 * i + 0], a0);
            a1 = dot2(av.y, wA[4 * i + 1], a1);
            a2 = dot2(av.z, wA[4 * i + 2], a2);
            a3 = dot2(av.w, wA[4 * i + 3], a3);
        }
        float acc = (a0 + a1) + (a2 + a3);
        acc += __shfl_xor(acc, 1);           // h0 + h1 -> full slice partial

        const uint32 tgt = (uint32)(t + 1);
        uint64* ex = exS + (size_t)(par * 64 + b) * (2 * 256);

        float sn = 0.f;
        if ((tid & 1) == 0) {
            // single 8B tagged store: payload + tag travel together
            uint64 u = ((uint64)tgt << 32) | (uint64)__float_as_uint(acc);
            __hip_atomic_store(ex + g * 256 + jA, u,
                               __ATOMIC_RELAXED, __HIP_MEMORY_SCOPE_AGENT);

            // poll the ONE peer word (it IS the payload); coalesced per wave
            const uint64* pp = ex + (1 - g) * 256 + jA;
            uint64 up;
            do {
                up = __hip_atomic_load(pp, __ATOMIC_RELAXED, __HIP_MEMORY_SCOPE_AGENT);
            } while ((uint32)(up >> 32) != tgt);

            float pre = acc + bs + __uint_as_float((uint32)up);  // fixed order
            // tanh(x) = 1 - 2/(exp(2x)+1): exact identity, branch-free
            float e = __expf(2.f * pre);
            sn = 1.f - 2.f / (e + 1.f);
        }
        {   // pack s pairs: threads 4m (jA=2m) and 4m+2 (jA=2m+1)
            float sno = __shfl_xor(sn, 2);
            if ((tid & 3) == 0) {
                int p = tid >> 2;                    // full-s pair index [0,128)
                uint32 sp2 = pkh(sn, sno);
                ((uint32*)s4pk)[p < 64 ? p : p + 4] = sp2;   // padded layout
                int d = p - 64 * g;                  // own s-half for next A
                if (d >= 0 && d < 64) wrp[128 + d] = sp2;
            }
        }
        bar_lds();                           // (1) s ready

        // ---- phase B: f[n], lane pair covers k=256 (padded: banks disjoint) ----
        float c0 = 0.f, c1 = 0.f, c2 = 0.f, c3 = 0.f;
        #pragma unroll
        for (int i = 0; i < 16; ++i) {
            uint4 sv = s4pk[17 * hh + i];    // 2 addrs/wave, different banks
            c0 = dot2(sv.x, wB[4 * i + 0], c0);
            c1 = dot2(sv.y, wB[4 * i + 1], c1);
            c2 = dot2(sv.z, wB[4 * i + 2], c2);
            c3 = dot2(sv.w, wB[4 * i + 3], c3);
        }
        float f = (c0 + c1) + (c2 + c3);
        f += __shfl_xor(f, 1);               // full k-sum at both pair lanes

        float xn = 0.f;
        if ((tid & 1) == 0) {
            float ff = fmaxf(f + bo_r, 0.f);
            float xo = xf32[nloc];           // exact f32 state in, f32 out
            xn = (xo + 0.1f * ff * Av_r) / (1.1f + 0.1f * ff);
            xf32[nloc] = xn;                 // same-thread RMW: no race
            out[outBase + (size_t)t * 512 + nloc] = xn;
        }
        {   // pack x pairs (fp16 copy feeds next A): threads 4m / 4m+2
            float xno = __shfl_xor(xn, 2);
            if ((tid & 3) == 0)
                wrp[tid >> 2] = pkh(xn, xno);
        }
        if (tid < 32) wrp[192 + tid] = pkh(iv2.x, iv2.y);   // stage I(t+1)
        bar_lds();                           // (2) state ready for next A
    }
}

extern "C" void kernel_launch(void* const* d_in, const int* in_sizes, int n_in,
                              void* d_out, int out_size, void* d_ws, size_t ws_size,
                              hipStream_t stream)
{
    const float* I     = (const float*)d_in[0];
    const float* W_ih  = (const float*)d_in[1];
    const float* W_hh  = (const float*)d_in[2];
    const float* b_ih  = (const float*)d_in[3];
    const float* b_hh  = (const float*)d_in[4];
    const float* W_out = (const float*)d_in[5];
    const float* b_out = (const float*)d_in[6];
    const float* A     = (const float*)d_in[7];

    uint32* WREGH = (uint32*)d_ws;
    uint64* exS   = (uint64*)((uint32*)d_ws + WREG_N);

    const int total = WREG_N + EXA_N;
    prep_kernel<<<(total + 1023) / 1024, 1024, 0, stream>>>(W_ih, W_hh, W_out,
                                                            WREGH, exS);
    scan_kernel<<<128, 512, 0, stream>>>(I, b_ih, b_hh, b_out, A,
                                         WREGH, exS, (float*)d_out);
}